// Round 15
// baseline (38.404 us; speedup 1.0000x reference)
//
#include <hip/hip_runtime.h>

#define NB 512
#define NATOMS 1024
#define NG 256
#define NL 8
#define NK 128

#define KBT 0.59616123f            // 0.0019872041 * 300
#define ALPHA_C 10.0f
#define LN2 0.6931471805599453f
#define LOG2E 1.4426950408889634f
#define INV2BW2 22.222221f         // 1/(2*0.15^2)
#define SCALE2 (INV2BW2 * LOG2E)   // log2-domain scale (~32.05)
#define LOG_NORM (-1.0170649f)     // log(128) + 3*log(2*pi*BW^2)

#define WL_CAP 2048                // max (g,l) pairs = NG*NL
#define FILL_BLOCKS 128            // 128*256*16B = 512 KiB = NG*NB*4B exactly
#define TR_BLOCKS 256              // (1024/32 atom-tiles) x (512/64 b-tiles)

typedef _Float16 f16x8 __attribute__((ext_vector_type(8)));
typedef float f32x16 __attribute__((ext_vector_type(16)));

__device__ __forceinline__ float fexp2(float x) { return __builtin_amdgcn_exp2f(x); }
__device__ __forceinline__ float flog2(float x) { return __builtin_amdgcn_logf(x); }

// monotone float<->uint key (unsigned order == float order), for atomicMin
__device__ __forceinline__ unsigned fkey(float f) {
  unsigned u = __float_as_uint(f);
  return (u & 0x80000000u) ? ~u : (u | 0x80000000u);
}
__device__ __forceinline__ float funkey(unsigned k) {
  unsigned u = (k & 0x80000000u) ? (k ^ 0x80000000u) : ~k;
  return __uint_as_float(u);
}

__device__ __forceinline__ float wred_min(float v) {
#pragma unroll
  for (int m = 32; m >= 1; m >>= 1) v = fminf(v, __shfl_xor(v, m, 64));
  return v;
}
__device__ __forceinline__ float wred_sum(float v) {
#pragma unroll
  for (int m = 32; m >= 1; m >>= 1) v += __shfl_xor(v, m, 64);
  return v;
}

// ---------------------------------------------------------------------------
// Combined prep.  bid 0: worklist prefix-sum.  bid 1..128: fill gmin_u keys.
// bid 129..384: TILED transpose positions[b][a][c] -> pT[a][c][b].
// Transpose tile = 32 atoms x 64 b's, staged in LDS (padded rows, conflict-
// free), BOTH global sides >=256B-contiguous and every 64B output line fully
// written by one thread (r8's scattered-store write-allocate amplification
// was the failure mode; this has none).
// ---------------------------------------------------------------------------
__global__ __launch_bounds__(256) void prep_small(
    const float* __restrict__ positions, const int* __restrict__ gsizes,
    int* __restrict__ wl, uint4* __restrict__ gmin_u4,
    float* __restrict__ pT) {
  const int t = threadIdx.x;
  const int bid = blockIdx.x;
  __shared__ int wsum[4];
  __shared__ float tile[64][97];           // [b][atom*3+c], +1 pad -> no conflicts

  if (bid == 0) {
    const int lane = t & 63, wid = t >> 6;
    int gs = gsizes[t];
    int nl = gs < 1 ? 1 : (gs > NL ? NL : gs);
    int x = nl;
#pragma unroll
    for (int m = 1; m < 64; m <<= 1) {
      int y = __shfl_up(x, m, 64);
      if (lane >= m) x += y;
    }
    if (lane == 63) wsum[wid] = x;
    __syncthreads();
    int off = 0;
    for (int i = 0; i < wid; ++i) off += wsum[i];
    int inc = off + x, exc = inc - nl;
    for (int j = 0; j < nl; ++j) wl[exc + j] = (t << 3) | j;   // entry == gl
    if (t == 255) wl[WL_CAP] = inc;
    return;
  }
  if (bid <= FILL_BLOCKS) {
    const unsigned F = 0xFFFFFFFFu;
    gmin_u4[(bid - 1) * 256 + t] = make_uint4(F, F, F, F);
    return;
  }

  // --- transpose tile: a0 = 32-atom tile, b0 = 64-b tile ---
  const int tb = bid - (FILL_BLOCKS + 1);
  const int a0 = (tb >> 3) << 5;
  const int b0 = (tb & 7) << 6;
  // read: 64 rows x 96 floats (24 float4 each), fully coalesced
#pragma unroll
  for (int iter = 0; iter < 6; ++iter) {
    const int fi = iter * 256 + t;
    const int i = fi / 24, s = fi - i * 24;
    const float4 v = *reinterpret_cast<const float4*>(
        positions + ((size_t)(b0 + i) * NATOMS + a0) * 3 + s * 4);
    tile[i][s * 4 + 0] = v.x;
    tile[i][s * 4 + 1] = v.y;
    tile[i][s * 4 + 2] = v.z;
    tile[i][s * 4 + 3] = v.w;
  }
  __syncthreads();
  // write: 96 pT rows x 64 b's; each thread owns one row -> 16 float4 stores,
  // 256B contiguous, each 64B line fully written by this thread.
  if (t < 96) {
    float* dst = pT + ((size_t)a0 * 3 + t) * NB + b0;
#pragma unroll
    for (int f = 0; f < 16; ++f) {
      float4 v = make_float4(tile[4 * f + 0][t], tile[4 * f + 1][t],
                             tile[4 * f + 2][t], tile[4 * f + 3][t]);
      *reinterpret_cast<float4*>(dst + 4 * f) = v;
    }
  }
}

// ---------------------------------------------------------------------------
// stage1 (r14 verified math, absmax 0.0): block = (entry w = bid>>2,
// b-quarter).  Block builds its gl's 8KB A-fragment table in LDS; two
// accumulating 32x32x16 MFMAs per 32-k tile; lane = one b (col=lane&31),
// 64 of its 128 k-values in registers, partner lane^32 the rest -> LSE =
// register tree + exactly 2 shuffles.  Position reads now COALESCED via pT
// (lane index == b): 12 dword loads, exact-line traffic.
// ---------------------------------------------------------------------------
__global__ __launch_bounds__(256) void stage1_kernel(
    const float* __restrict__ pT, const float* __restrict__ kde,
    const float* __restrict__ weight, const float* __restrict__ offs,
    const int* __restrict__ atom_idxs, const int* __restrict__ wl,
    unsigned* __restrict__ gmin_u) {
  const int count = wl[WL_CAP];
  const int w = blockIdx.x >> 2;
  if (w >= count) return;                  // contiguous inactive tail
  const int gl = wl[w];
  const int g = gl >> 3;

  const int t = threadIdx.x;
  const int lane = t & 63;
  const int col = lane & 31, h = lane >> 5;
  const int b = ((blockIdx.x & 3) << 7) + ((t >> 6) << 5) + col;

  __shared__ f16x8 tabL[8][64];            // [kt*2+j][lane], 8 KiB

  // --- coalesced position reads via pT (issued first; hide under build) ---
  const int4 idx = *reinterpret_cast<const int4*>(atom_idxs + (gl << 2));
  const int ids[4] = {idx.x, idx.y, idx.z, idx.w};
  float ax[4], ay[4], az[4];
#pragma unroll
  for (int j = 0; j < 4; ++j) {
    const float* pr = pT + (size_t)ids[j] * 3 * NB + b;
    ax[j] = pr[0];
    ay[j] = pr[NB];
    az[j] = pr[2 * NB];
  }

  // --- build the fragment table: thread k (0..127) fills 4 f16x8 slots ---
  if (t < NK) {
    const float* mp = kde + ((size_t)gl * NK + t) * 6;
    float mu2 = 0.0f;
    _Float16 ah[6], al[6];
#pragma unroll
    for (int q = 0; q < 6; ++q) {
      float mv = mp[q];
      mu2 += mv * mv;
      float a = (2.0f * SCALE2) * mv;
      _Float16 hh = (_Float16)a;
      ah[q] = hh;
      al[q] = (_Float16)(a - (float)hh);
    }
    float z = -SCALE2 * mu2;
    _Float16 z1 = (_Float16)z;
    _Float16 z2 = (_Float16)(z - (float)z1);
    const _Float16 Z = (_Float16)0.0f;
    const int kt = t >> 5, m = t & 31;
    tabL[kt * 2 + 0][m]      = (f16x8){ah[0],ah[1],ah[2],ah[3],ah[4],ah[5],al[0],al[1]};
    tabL[kt * 2 + 0][m + 32] = (f16x8){al[2],al[3],al[4],al[5],ah[0],ah[1],ah[2],ah[3]};
    tabL[kt * 2 + 1][m]      = (f16x8){ah[4],ah[5],al[0],al[1],al[2],al[3],al[4],al[5]};
    tabL[kt * 2 + 1][m + 32] = (f16x8){z1,  z2,  Z,   Z,   Z,   Z,   Z,   Z   };
  }

  // --- distances + B-fragments (overlaps table build) ---
  const int PI_[6] = {0, 0, 0, 1, 1, 2};
  const int PJ_[6] = {1, 2, 3, 2, 3, 3};
  float d[6]; float x2 = 0.0f;
#pragma unroll
  for (int q = 0; q < 6; ++q) {
    float dx = ax[PI_[q]] - ax[PJ_[q]];
    float dy = ay[PI_[q]] - ay[PJ_[q]];
    float dz = az[PI_[q]] - az[PJ_[q]];
    float dd = dx * dx + dy * dy + dz * dz + 1e-12f;
    d[q] = sqrtf(dd);
    x2 += d[q] * d[q];
  }
  const float c2 = -x2 * SCALE2;           // per-b constant (log2 domain)

  _Float16 xh[6], xl[6];
#pragma unroll
  for (int q = 0; q < 6; ++q) {
    _Float16 hh = (_Float16)d[q];
    xh[q] = hh;
    xl[q] = (_Float16)(d[q] - (float)hh);
  }
  const _Float16 ONE = (_Float16)1.0f, Z = (_Float16)0.0f;
  f16x8 Bf0 = (h == 0)
    ? (f16x8){xh[0],xh[1],xh[2],xh[3],xh[4],xh[5],xh[0],xh[1]}
    : (f16x8){xh[2],xh[3],xh[4],xh[5],xl[0],xl[1],xl[2],xl[3]};
  f16x8 Bf1 = (h == 0)
    ? (f16x8){xl[4],xl[5],xl[0],xl[1],xl[2],xl[3],xl[4],xl[5]}
    : (f16x8){ONE,  ONE,  Z,   Z,   Z,   Z,   Z,   Z   };

  __syncthreads();

  // --- 4 k-tiles x 2 accumulating MFMAs; A-frags from LDS per tile ---
  const f32x16 zz = {0.0f};
  f32x16 acc[4];
#pragma unroll
  for (int kt = 0; kt < 4; ++kt) {
    f16x8 A0 = tabL[kt * 2 + 0][lane];
    f16x8 A1 = tabL[kt * 2 + 1][lane];
    acc[kt] = __builtin_amdgcn_mfma_f32_32x32x16_f16(
        A1, Bf1, __builtin_amdgcn_mfma_f32_32x32x16_f16(A0, Bf0, zz, 0, 0, 0),
        0, 0, 0);
  }

  // --- LSE over 128 k: 64 in registers + partner lane (1 shfl each) ---
  float mkt[4];
#pragma unroll
  for (int kt = 0; kt < 4; ++kt) {
    float m0 = fmaxf(fmaxf(acc[kt][0], acc[kt][1]), fmaxf(acc[kt][2], acc[kt][3]));
    float m1 = fmaxf(fmaxf(acc[kt][4], acc[kt][5]), fmaxf(acc[kt][6], acc[kt][7]));
    float m2 = fmaxf(fmaxf(acc[kt][8], acc[kt][9]), fmaxf(acc[kt][10], acc[kt][11]));
    float m3 = fmaxf(fmaxf(acc[kt][12], acc[kt][13]), fmaxf(acc[kt][14], acc[kt][15]));
    mkt[kt] = fmaxf(fmaxf(m0, m1), fmaxf(m2, m3));
  }
  float mx = fmaxf(fmaxf(mkt[0], mkt[1]), fmaxf(mkt[2], mkt[3]));
  mx = fmaxf(mx, __shfl_xor(mx, 32, 64));

  float s0 = 0.0f, s1 = 0.0f, s2 = 0.0f, s3 = 0.0f;
#pragma unroll
  for (int kt = 0; kt < 4; ++kt) {
    s0 += fexp2(acc[kt][0] - mx)  + fexp2(acc[kt][1] - mx)
        + fexp2(acc[kt][2] - mx)  + fexp2(acc[kt][3] - mx);
    s1 += fexp2(acc[kt][4] - mx)  + fexp2(acc[kt][5] - mx)
        + fexp2(acc[kt][6] - mx)  + fexp2(acc[kt][7] - mx);
    s2 += fexp2(acc[kt][8] - mx)  + fexp2(acc[kt][9] - mx)
        + fexp2(acc[kt][10] - mx) + fexp2(acc[kt][11] - mx);
    s3 += fexp2(acc[kt][12] - mx) + fexp2(acc[kt][13] - mx)
        + fexp2(acc[kt][14] - mx) + fexp2(acc[kt][15] - mx);
  }
  float s = (s0 + s1) + (s2 + s3);
  s += __shfl_xor(s, 32, 64);

  if (h == 0) {
    float lse2 = c2 + mx + flog2(s);       // log2(sum_k exp(v_k))
    float logP = lse2 * LN2 - LOG_NORM;
    float scaled = -KBT * logP * weight[gl] + offs[gl];
    atomicMin(&gmin_u[g * NB + b], fkey(scaled));
  }
}

// One block per b: min over g, then logsumexp(-ALPHA*gmin) over g.
__global__ __launch_bounds__(256) void stage2_kernel(
    const unsigned* __restrict__ gmin_u, float* __restrict__ out) {
  const int b = blockIdx.x;
  const int t = threadIdx.x;
  const int lane = t & 63;
  const int wid = t >> 6;
  float v = funkey(gmin_u[t * NB + b]);
  __shared__ float sm[4], ss[4];
  float m = wred_min(v);
  if (lane == 0) sm[wid] = m;
  __syncthreads();
  float M = fminf(fminf(sm[0], sm[1]), fminf(sm[2], sm[3]));
  float e = fexp2(-ALPHA_C * LOG2E * (v - M));
  float s = wred_sum(e);
  if (lane == 0) ss[wid] = s;
  __syncthreads();
  if (t == 0) {
    float S = ss[0] + ss[1] + ss[2] + ss[3];
    out[b] = M - flog2(S) * LN2 / ALPHA_C;
  }
}

extern "C" void kernel_launch(void* const* d_in, const int* in_sizes, int n_in,
                              void* d_out, int out_size, void* d_ws, size_t ws_size,
                              hipStream_t stream) {
  const float* positions = (const float*)d_in[0];
  const float* kde       = (const float*)d_in[1];
  const float* weight    = (const float*)d_in[2];
  const float* offs      = (const float*)d_in[3];
  const int*   atom_idxs = (const int*)d_in[4];
  const int*   gsizes    = (const int*)d_in[5];
  float* out = (float*)d_out;

  unsigned* gmin_u = (unsigned*)d_ws;                     // 512 KiB @ 0
  int* wl = (int*)d_ws + (size_t)NG * NB;                 // ~8 KiB @ 512 KiB
  float* pT = (float*)((char*)d_ws + (1 << 20));          // 6.3 MiB @ 1 MiB

  prep_small<<<dim3(1 + FILL_BLOCKS + TR_BLOCKS), dim3(256), 0, stream>>>(
      positions, gsizes, wl, (uint4*)gmin_u, pT);
  stage1_kernel<<<dim3(WL_CAP * 4), dim3(256), 0, stream>>>(
      pT, kde, weight, offs, atom_idxs, wl, gmin_u);
  stage2_kernel<<<dim3(NB), dim3(256), 0, stream>>>(gmin_u, out);
}

// Round 16
// 37.731 us; speedup vs baseline: 1.0179x; 1.0179x over previous
//
#include <hip/hip_runtime.h>

#define NB 512
#define NATOMS 1024
#define NG 256
#define NL 8
#define NK 128

#define KBT 0.59616123f            // 0.0019872041 * 300
#define ALPHA_C 10.0f
#define LN2 0.6931471805599453f
#define LOG2E 1.4426950408889634f
#define INV2BW2 22.222221f         // 1/(2*0.15^2)
#define SCALE2 (INV2BW2 * LOG2E)   // log2-domain scale (~32.05)
#define LOG_NORM (-1.0170649f)     // log(128) + 3*log(2*pi*BW^2)

#define WL_CAP 2048                // max (g,l) pairs = NG*NL
#define FILL_BLOCKS 128            // 128*256*16B = 512 KiB = NG*NB*4B exactly

typedef _Float16 f16x8 __attribute__((ext_vector_type(8)));
typedef float f32x16 __attribute__((ext_vector_type(16)));

__device__ __forceinline__ float fexp2(float x) { return __builtin_amdgcn_exp2f(x); }
__device__ __forceinline__ float flog2(float x) { return __builtin_amdgcn_logf(x); }

// monotone float<->uint key (unsigned order == float order), for atomicMin
__device__ __forceinline__ unsigned fkey(float f) {
  unsigned u = __float_as_uint(f);
  return (u & 0x80000000u) ? ~u : (u | 0x80000000u);
}
__device__ __forceinline__ float funkey(unsigned k) {
  unsigned u = (k & 0x80000000u) ? (k ^ 0x80000000u) : ~k;
  return __uint_as_float(u);
}

__device__ __forceinline__ float wred_min(float v) {
#pragma unroll
  for (int m = 32; m >= 1; m >>= 1) v = fminf(v, __shfl_xor(v, m, 64));
  return v;
}
__device__ __forceinline__ float wred_sum(float v) {
#pragma unroll
  for (int m = 32; m >= 1; m >>= 1) v += __shfl_xor(v, m, 64);
  return v;
}

// Grid = 1 + FILL_BLOCKS.  Block 0: prefix-sum nl -> packed worklist of
// active (g,l) pairs (wl[WL_CAP] = count).  Blocks 1..: fill gmin_u keys.
__global__ __launch_bounds__(256) void prep_small(
    const int* __restrict__ gsizes, int* __restrict__ wl,
    uint4* __restrict__ gmin_u4) {
  const int t = threadIdx.x;
  if (blockIdx.x != 0) {
    const unsigned F = 0xFFFFFFFFu;
    gmin_u4[(blockIdx.x - 1) * 256 + t] = make_uint4(F, F, F, F);
    return;
  }
  const int lane = t & 63, wid = t >> 6;
  int gs = gsizes[t];
  int nl = gs < 1 ? 1 : (gs > NL ? NL : gs);
  int x = nl;
#pragma unroll
  for (int m = 1; m < 64; m <<= 1) {
    int y = __shfl_up(x, m, 64);
    if (lane >= m) x += y;
  }
  __shared__ int wsum[4];
  if (lane == 63) wsum[wid] = x;
  __syncthreads();
  int off = 0;
  for (int i = 0; i < wid; ++i) off += wsum[i];
  int inc = off + x, exc = inc - nl;
  for (int j = 0; j < nl; ++j) wl[exc + j] = (t << 3) | j;   // entry == gl
  if (t == 255) wl[WL_CAP] = inc;
}

// ---------------------------------------------------------------------------
// stage1: ONE block per worklist entry, covering ALL 512 b's.
//   - table built ONCE per entry (r14 built it 4x: 3680 vs 920 builds, each
//     paying the kde-load barrier stall)
//   - each wave processes 4 b-groups of 32 sequentially, reusing the LDS
//     table and the acc registers (VGPR ~124 -> 4 waves/SIMD)
//   - position gathers for group gg+1 are double-buffered: issued during
//     group gg's compute, so gather latency hides under ~800cyc of work
// Math bit-identical to r13/r14 (absmax 0.0): two accumulating 32x32x16
// MFMAs per 32-k tile; fp16-split contraction; LSE = register tree + 2
// shuffles (partner lane^32).
// ---------------------------------------------------------------------------
__global__ __launch_bounds__(256) void stage1_kernel(
    const float* __restrict__ positions, const float* __restrict__ kde,
    const float* __restrict__ weight, const float* __restrict__ offs,
    const int* __restrict__ atom_idxs, const int* __restrict__ wl,
    unsigned* __restrict__ gmin_u) {
  const int count = wl[WL_CAP];
  const int w = blockIdx.x;
  if (w >= count) return;                  // contiguous inactive tail
  const int gl = wl[w];
  const int g = gl >> 3;

  const int t = threadIdx.x;
  const int lane = t & 63;
  const int wid = t >> 6;
  const int col = lane & 31, h = lane >> 5;

  __shared__ f16x8 tabL[8][64];            // [kt*2+j][lane], 8 KiB

  const int4 idx = *reinterpret_cast<const int4*>(atom_idxs + (gl << 2));
  const int ids[4] = {idx.x, idx.y, idx.z, idx.w};

  // --- group-0 gather issued first (hides under the table build) ---
  float px[2][4], py[2][4], pz[2][4];
  {
    const int b = (wid << 5) + col;        // gg = 0
    const float* pb = positions + (size_t)b * NATOMS * 3;
#pragma unroll
    for (int j = 0; j < 4; ++j) {
      const float3 p = *reinterpret_cast<const float3*>(pb + ids[j] * 3);
      px[0][j] = p.x; py[0][j] = p.y; pz[0][j] = p.z;
    }
  }

  // --- build the fragment table: thread k (0..127) fills 4 f16x8 slots ---
  if (t < NK) {
    const float* mp = kde + ((size_t)gl * NK + t) * 6;
    float mu2 = 0.0f;
    _Float16 ah[6], al[6];
#pragma unroll
    for (int q = 0; q < 6; ++q) {
      float mv = mp[q];
      mu2 += mv * mv;
      float a = (2.0f * SCALE2) * mv;
      _Float16 hh = (_Float16)a;
      ah[q] = hh;
      al[q] = (_Float16)(a - (float)hh);
    }
    float z = -SCALE2 * mu2;
    _Float16 z1 = (_Float16)z;
    _Float16 z2 = (_Float16)(z - (float)z1);
    const _Float16 Z = (_Float16)0.0f;
    const int kt = t >> 5, m = t & 31;
    tabL[kt * 2 + 0][m]      = (f16x8){ah[0],ah[1],ah[2],ah[3],ah[4],ah[5],al[0],al[1]};
    tabL[kt * 2 + 0][m + 32] = (f16x8){al[2],al[3],al[4],al[5],ah[0],ah[1],ah[2],ah[3]};
    tabL[kt * 2 + 1][m]      = (f16x8){ah[4],ah[5],al[0],al[1],al[2],al[3],al[4],al[5]};
    tabL[kt * 2 + 1][m + 32] = (f16x8){z1,  z2,  Z,   Z,   Z,   Z,   Z,   Z   };
  }
  __syncthreads();

  const float wgt = weight[gl], off = offs[gl];
  const int PI_[6] = {0, 0, 0, 1, 1, 2};
  const int PJ_[6] = {1, 2, 3, 2, 3, 3};
  const _Float16 ONE = (_Float16)1.0f, Z = (_Float16)0.0f;
  const f32x16 zz = {0.0f};

#pragma unroll
  for (int gg = 0; gg < 4; ++gg) {
    const int cur = gg & 1;
    // prefetch next group's positions (overlaps this group's compute)
    if (gg < 3) {
      const int bn = ((gg + 1) << 7) + (wid << 5) + col;
      const float* pb = positions + (size_t)bn * NATOMS * 3;
#pragma unroll
      for (int j = 0; j < 4; ++j) {
        const float3 p = *reinterpret_cast<const float3*>(pb + ids[j] * 3);
        px[cur ^ 1][j] = p.x; py[cur ^ 1][j] = p.y; pz[cur ^ 1][j] = p.z;
      }
    }
    const int b = (gg << 7) + (wid << 5) + col;

    // distances
    float d[6]; float x2 = 0.0f;
#pragma unroll
    for (int q = 0; q < 6; ++q) {
      float dx = px[cur][PI_[q]] - px[cur][PJ_[q]];
      float dy = py[cur][PI_[q]] - py[cur][PJ_[q]];
      float dz = pz[cur][PI_[q]] - pz[cur][PJ_[q]];
      float dd = dx * dx + dy * dy + dz * dz + 1e-12f;
      d[q] = sqrtf(dd);
      x2 += d[q] * d[q];
    }
    const float c2 = -x2 * SCALE2;         // per-b constant (log2 domain)

    // B-fragments: 2-way fp16 split, chunk by lane-half (matches table)
    _Float16 xh[6], xl[6];
#pragma unroll
    for (int q = 0; q < 6; ++q) {
      _Float16 hh = (_Float16)d[q];
      xh[q] = hh;
      xl[q] = (_Float16)(d[q] - (float)hh);
    }
    f16x8 Bf0 = (h == 0)
      ? (f16x8){xh[0],xh[1],xh[2],xh[3],xh[4],xh[5],xh[0],xh[1]}
      : (f16x8){xh[2],xh[3],xh[4],xh[5],xl[0],xl[1],xl[2],xl[3]};
    f16x8 Bf1 = (h == 0)
      ? (f16x8){xl[4],xl[5],xl[0],xl[1],xl[2],xl[3],xl[4],xl[5]}
      : (f16x8){ONE,  ONE,  Z,   Z,   Z,   Z,   Z,   Z   };

    // 4 k-tiles x 2 accumulating MFMAs; A-frags from LDS
    f32x16 acc[4];
#pragma unroll
    for (int kt = 0; kt < 4; ++kt) {
      f16x8 A0 = tabL[kt * 2 + 0][lane];
      f16x8 A1 = tabL[kt * 2 + 1][lane];
      acc[kt] = __builtin_amdgcn_mfma_f32_32x32x16_f16(
          A1, Bf1, __builtin_amdgcn_mfma_f32_32x32x16_f16(A0, Bf0, zz, 0, 0, 0),
          0, 0, 0);
    }

    // LSE over 128 k: 64 in registers + partner lane (1 shfl each)
    float mkt[4];
#pragma unroll
    for (int kt = 0; kt < 4; ++kt) {
      float m0 = fmaxf(fmaxf(acc[kt][0], acc[kt][1]), fmaxf(acc[kt][2], acc[kt][3]));
      float m1 = fmaxf(fmaxf(acc[kt][4], acc[kt][5]), fmaxf(acc[kt][6], acc[kt][7]));
      float m2 = fmaxf(fmaxf(acc[kt][8], acc[kt][9]), fmaxf(acc[kt][10], acc[kt][11]));
      float m3 = fmaxf(fmaxf(acc[kt][12], acc[kt][13]), fmaxf(acc[kt][14], acc[kt][15]));
      mkt[kt] = fmaxf(fmaxf(m0, m1), fmaxf(m2, m3));
    }
    float mx = fmaxf(fmaxf(mkt[0], mkt[1]), fmaxf(mkt[2], mkt[3]));
    mx = fmaxf(mx, __shfl_xor(mx, 32, 64));

    float s0 = 0.0f, s1 = 0.0f, s2 = 0.0f, s3 = 0.0f;
#pragma unroll
    for (int kt = 0; kt < 4; ++kt) {
      s0 += fexp2(acc[kt][0] - mx)  + fexp2(acc[kt][1] - mx)
          + fexp2(acc[kt][2] - mx)  + fexp2(acc[kt][3] - mx);
      s1 += fexp2(acc[kt][4] - mx)  + fexp2(acc[kt][5] - mx)
          + fexp2(acc[kt][6] - mx)  + fexp2(acc[kt][7] - mx);
      s2 += fexp2(acc[kt][8] - mx)  + fexp2(acc[kt][9] - mx)
          + fexp2(acc[kt][10] - mx) + fexp2(acc[kt][11] - mx);
      s3 += fexp2(acc[kt][12] - mx) + fexp2(acc[kt][13] - mx)
          + fexp2(acc[kt][14] - mx) + fexp2(acc[kt][15] - mx);
    }
    float s = (s0 + s1) + (s2 + s3);
    s += __shfl_xor(s, 32, 64);

    if (h == 0) {
      float lse2 = c2 + mx + flog2(s);     // log2(sum_k exp(v_k))
      float logP = lse2 * LN2 - LOG_NORM;
      float scaled = -KBT * logP * wgt + off;
      atomicMin(&gmin_u[g * NB + b], fkey(scaled));
    }
  }
}

// One block per b: min over g, then logsumexp(-ALPHA*gmin) over g.
__global__ __launch_bounds__(256) void stage2_kernel(
    const unsigned* __restrict__ gmin_u, float* __restrict__ out) {
  const int b = blockIdx.x;
  const int t = threadIdx.x;
  const int lane = t & 63;
  const int wid = t >> 6;
  float v = funkey(gmin_u[t * NB + b]);
  __shared__ float sm[4], ss[4];
  float m = wred_min(v);
  if (lane == 0) sm[wid] = m;
  __syncthreads();
  float M = fminf(fminf(sm[0], sm[1]), fminf(sm[2], sm[3]));
  float e = fexp2(-ALPHA_C * LOG2E * (v - M));
  float s = wred_sum(e);
  if (lane == 0) ss[wid] = s;
  __syncthreads();
  if (t == 0) {
    float S = ss[0] + ss[1] + ss[2] + ss[3];
    out[b] = M - flog2(S) * LN2 / ALPHA_C;
  }
}

extern "C" void kernel_launch(void* const* d_in, const int* in_sizes, int n_in,
                              void* d_out, int out_size, void* d_ws, size_t ws_size,
                              hipStream_t stream) {
  const float* positions = (const float*)d_in[0];
  const float* kde       = (const float*)d_in[1];
  const float* weight    = (const float*)d_in[2];
  const float* offs      = (const float*)d_in[3];
  const int*   atom_idxs = (const int*)d_in[4];
  const int*   gsizes    = (const int*)d_in[5];
  float* out = (float*)d_out;

  unsigned* gmin_u = (unsigned*)d_ws;                     // 512 KiB @ 0
  int* wl = (int*)d_ws + (size_t)NG * NB;                 // ~8 KiB @ 512 KiB

  prep_small<<<dim3(1 + FILL_BLOCKS), dim3(256), 0, stream>>>(
      gsizes, wl, (uint4*)gmin_u);
  stage1_kernel<<<dim3(WL_CAP), dim3(256), 0, stream>>>(
      positions, kde, weight, offs, atom_idxs, wl, gmin_u);
  stage2_kernel<<<dim3(NB), dim3(256), 0, stream>>>(gmin_u, out);
}